// Round 11
// baseline (24.084 us; speedup 1.0000x reference)
//
#include <hip/hip_runtime.h>
#include <hip/hip_bf16.h>

#define NEGC (-1e8f)

__device__ __forceinline__ float lrelu(float x) { return x >= 0.f ? x : 0.2f * x; }

// Edge-logit computation. MUST be bit-identical between the stats pass (k2)
// and the output pass (k3): the neg-mask multiplies e by -1e8, so a 1-ulp
// difference becomes ~±50 in the logit and exp() explodes. Add/mul only,
// fixed association e = ss + soj. k1 is the SINGLE producer of soj bits
// (sojd[j]); k2/k3 both reload them -> consistency by construction.
__device__ __forceinline__ void edge_pq(float ss, float soj, bool same,
                                        float& p, float& q) {
    float e = ss + soj;
    float pin = same ? e : e * NEGC;
    float nin = same ? e * NEGC : e;
    p = lrelu(pin);
    q = lrelu(nin);
}

// ---------------- Kernel 1: scores. 8 blocks x 512 thr. Produces s_self[i]
// and sojd[j] = (node[j]·u1 + c1) + b_att (the one fixed association).
__global__ __launch_bounds__(512) void k1_scores(
        const float* __restrict__ node,
        const float* __restrict__ W_emb,
        const float* __restrict__ b_emb,
        const float* __restrict__ w_att,
        const float* __restrict__ b_att,
        float* __restrict__ sojd_g, float* __restrict__ s_self_g) {
    int t = threadIdx.x;
    int b = blockIdx.x;

    __shared__ float part[1024];
    __shared__ float u1[128], u2[128];
    __shared__ float cc[2];

    // u1/u2 partials: quarter q of the e-range, column k
    {
        int k = t & 127, q = t >> 7;
        float p1 = 0.f, p2 = 0.f;
        for (int e = 32 * q; e < 32 * q + 32; ++e) {
            float w = W_emb[e * 128 + k];
            p1 += w * w_att[e];
            p2 += w * w_att[128 + e];
        }
        part[q * 256 + k] = p1;
        part[q * 256 + 128 + k] = p2;
    }
    __syncthreads();
    if (t < 128) {
        u1[t] = part[t] + part[256 + t] + part[512 + t] + part[768 + t];
    } else if (t < 256) {
        int k = t - 128;
        u2[k] = part[128 + k] + part[384 + k] + part[640 + k] + part[896 + k];
    } else if (t < 320) {              // c1 = dot(b_emb, w_att[:128])
        int l = t - 256;
        float c = b_emb[l] * w_att[l] + b_emb[64 + l] * w_att[64 + l];
        for (int off = 32; off > 0; off >>= 1) c += __shfl_xor(c, off, 64);
        if (l == 0) cc[0] = c;
    } else if (t < 384) {              // c2 = dot(b_emb, w_att[128:])
        int l = t - 320;
        float c = b_emb[l] * w_att[128 + l] + b_emb[64 + l] * w_att[192 + l];
        for (int off = 32; off > 0; off >>= 1) c += __shfl_xor(c, off, 64);
        if (l == 0) cc[1] = c;
    }
    __syncthreads();

    // scores: row = b*128 + t/4; quarter q = t&3 covers 32 elems (8 float4)
    {
        int row = b * 128 + (t >> 2);
        int q = t & 3;
        const float4* row4 = (const float4*)(node + (size_t)row * 128);
        const float4* u14 = (const float4*)u1;
        const float4* u24 = (const float4*)u2;
        float d1 = 0.f, d2 = 0.f;
#pragma unroll
        for (int k = 0; k < 8; ++k) {
            float4 x = row4[q * 8 + k];
            float4 v1 = u14[q * 8 + k];
            float4 v2 = u24[q * 8 + k];
            d1 += x.x * v1.x + x.y * v1.y + x.z * v1.z + x.w * v1.w;
            d2 += x.x * v2.x + x.y * v2.y + x.z * v2.z + x.w * v2.w;
        }
        d1 += __shfl_xor(d1, 1, 64); d1 += __shfl_xor(d1, 2, 64);
        d2 += __shfl_xor(d2, 1, 64); d2 += __shfl_xor(d2, 2, 64);
        if (q == 0) {
            sojd_g[row]   = (d1 + cc[0]) + b_att[0];  // THE association
            s_self_g[row] = d2 + cc[1];
        }
    }
}

// ---------------- Kernel 2: per-column softmax stats. 128 blocks x 256 thr;
// wave wv handles TWO columns (shares the s_self/group vector loads).
// float4/int4 loads: lane holds rows 4*(k*64+lane)+{0..3}, k=0..3.
// Max pass keeps a 16-bit same-mask; sum pass recomputes edge_pq (cheap ALU)
// instead of holding 32 logit registers. pmax bit-exact (max is order-free);
// sum order only perturbs alpha by ~1e-7 relative (threshold 9.0).
__global__ __launch_bounds__(256) void k2_col_stats(
        const float* __restrict__ s_self,
        const int* __restrict__ group,
        const float* __restrict__ sojd,
        float4* __restrict__ stats4) {
    int wv = threadIdx.x >> 6, lane = threadIdx.x & 63;
    int j0 = blockIdx.x * 8 + wv * 2;

    float soj0 = sojd[j0], soj1 = sojd[j0 + 1];
    int g0 = group[j0], g1 = group[j0 + 1];

    const float4* ss4 = (const float4*)s_self;
    const int4*   gp4 = (const int4*)group;
    float4 sv[4]; int4 gv[4];
#pragma unroll
    for (int k = 0; k < 4; ++k) {
        sv[k] = ss4[k * 64 + lane];
        gv[k] = gp4[k * 64 + lane];
    }

    float pm0 = -3.4e38f, nm0 = -3.4e38f, pm1 = -3.4e38f, nm1 = -3.4e38f;
    unsigned m0 = 0, m1 = 0;   // same-masks, bit (k*4+e)
#pragma unroll
    for (int k = 0; k < 4; ++k) {
        float s[4] = {sv[k].x, sv[k].y, sv[k].z, sv[k].w};
        int   gi[4] = {gv[k].x, gv[k].y, gv[k].z, gv[k].w};
#pragma unroll
        for (int e = 0; e < 4; ++e) {
            bool sm0 = (gi[e] == g0), sm1 = (gi[e] == g1);
            m0 |= (unsigned)sm0 << (k * 4 + e);
            m1 |= (unsigned)sm1 << (k * 4 + e);
            float p, q;
            edge_pq(s[e], soj0, sm0, p, q);
            pm0 = fmaxf(pm0, p); nm0 = fmaxf(nm0, q);
            edge_pq(s[e], soj1, sm1, p, q);
            pm1 = fmaxf(pm1, p); nm1 = fmaxf(nm1, q);
        }
    }
#pragma unroll
    for (int off = 32; off > 0; off >>= 1) {
        pm0 = fmaxf(pm0, __shfl_xor(pm0, off, 64));
        nm0 = fmaxf(nm0, __shfl_xor(nm0, off, 64));
        pm1 = fmaxf(pm1, __shfl_xor(pm1, off, 64));
        nm1 = fmaxf(nm1, __shfl_xor(nm1, off, 64));
    }

    float ps0 = 0.f, ns0 = 0.f, ps1 = 0.f, ns1 = 0.f;
#pragma unroll
    for (int k = 0; k < 4; ++k) {
        float s[4] = {sv[k].x, sv[k].y, sv[k].z, sv[k].w};
#pragma unroll
        for (int e = 0; e < 4; ++e) {
            bool sm0 = (m0 >> (k * 4 + e)) & 1, sm1 = (m1 >> (k * 4 + e)) & 1;
            float p, q;
            edge_pq(s[e], soj0, sm0, p, q);
            ps0 += __expf(p - pm0); ns0 += __expf(q - nm0);
            edge_pq(s[e], soj1, sm1, p, q);
            ps1 += __expf(p - pm1); ns1 += __expf(q - nm1);
        }
    }
#pragma unroll
    for (int off = 32; off > 0; off >>= 1) {
        ps0 += __shfl_xor(ps0, off, 64);
        ns0 += __shfl_xor(ns0, off, 64);
        ps1 += __shfl_xor(ps1, off, 64);
        ns1 += __shfl_xor(ns1, off, 64);
    }
    if (lane == 0) {
        stats4[j0]     = make_float4(pm0, 1.f / ps0, nm0, 1.f / ns0);
        stats4[j0 + 1] = make_float4(pm1, 1.f / ps1, nm1, 1.f / ns1);
    }
}

// ---------------- Kernel 3: out[i,:] = sum_j A[i,j] * relu(node[j,:])
// BI=4 rows/block, 256 blocks x 512 thr (R10-proven, verbatim).
#define BI 4
__global__ __launch_bounds__(512) void k3_out(
        const float* __restrict__ node,
        const float* __restrict__ s_self,
        const int* __restrict__ group,
        const float* __restrict__ sojd,
        const float4* __restrict__ stats4,
        float* __restrict__ out) {
    int t = threadIdx.x;       // 0..511
    int i0 = blockIdx.x * BI;

    __shared__ float buf[8192];   // 32 KB: first 1024 float4 = bufA, then reduce
    __shared__ float ss_l[BI];
    __shared__ int   g_l[BI];
    if (t < BI) { ss_l[t] = s_self[i0 + t]; g_l[t] = group[i0 + t]; }
    __syncthreads();

    float ssr[BI]; int glr[BI];
#pragma unroll
    for (int r = 0; r < BI; ++r) { ssr[r] = ss_l[r]; glr[r] = g_l[r]; }

    float4* bufA = (float4*)buf;
#pragma unroll
    for (int e = 0; e < 2; ++e) {
        int j = t + e * 512;
        float soj = sojd[j];            // exact bits k1 produced, k2 consumed
        float4 st = stats4[j];
        int gj = group[j];
        float a[BI];
#pragma unroll
        for (int r = 0; r < BI; ++r) {
            float p, q;
            edge_pq(ssr[r], soj, gj == glr[r], p, q);
            a[r] = __expf(p - st.x) * st.y + __expf(q - st.z) * st.w;
        }
        bufA[j] = make_float4(a[0], a[1], a[2], a[3]);
    }
    __syncthreads();

    int lane = t & 31;   // float4 index within a 128-d row
    int g = t >> 5;      // j-group 0..15
    const float4* nf4 = (const float4*)node;

    float4 acc[BI];
#pragma unroll
    for (int r = 0; r < BI; ++r) acc[r] = make_float4(0.f, 0.f, 0.f, 0.f);

#pragma unroll 8
    for (int j = g; j < 1024; j += 16) {
        float4 x = nf4[(size_t)j * 32 + lane];
        float4 rn;
        rn.x = fmaxf(x.x, 0.f); rn.y = fmaxf(x.y, 0.f);
        rn.z = fmaxf(x.z, 0.f); rn.w = fmaxf(x.w, 0.f);
        float4 a4 = bufA[j];            // broadcast b128
        acc[0].x += a4.x * rn.x; acc[0].y += a4.x * rn.y;
        acc[0].z += a4.x * rn.z; acc[0].w += a4.x * rn.w;
        acc[1].x += a4.y * rn.x; acc[1].y += a4.y * rn.y;
        acc[1].z += a4.y * rn.z; acc[1].w += a4.y * rn.w;
        acc[2].x += a4.z * rn.x; acc[2].y += a4.z * rn.y;
        acc[2].z += a4.z * rn.z; acc[2].w += a4.z * rn.w;
        acc[3].x += a4.w * rn.x; acc[3].y += a4.w * rn.y;
        acc[3].z += a4.w * rn.z; acc[3].w += a4.w * rn.w;
    }

    __syncthreads();  // done reading bufA; reuse buf as reduce buffer
    float4* red = (float4*)buf;   // red[g*128 + r*32 + lane], 2048 float4
#pragma unroll
    for (int r = 0; r < BI; ++r) red[g * 128 + r * 32 + lane] = acc[r];
    __syncthreads();

    // 512 outputs (BI rows x 128 d); 1 per thread, contiguous store
    int r = t >> 7;
    int d = t & 127;
    float sum = 0.f;
#pragma unroll
    for (int gg = 0; gg < 16; ++gg)
        sum += buf[gg * 512 + r * 128 + d];
    out[(size_t)(i0 + r) * 128 + d] = sum;
}

extern "C" void kernel_launch(void* const* d_in, const int* in_sizes, int n_in,
                              void* d_out, int out_size, void* d_ws, size_t ws_size,
                              hipStream_t stream) {
    const float* node  = (const float*)d_in[0];
    const int*   group = (const int*)d_in[1];
    const float* W_emb = (const float*)d_in[2];
    const float* b_emb = (const float*)d_in[3];
    const float* w_att = (const float*)d_in[4];
    const float* b_att = (const float*)d_in[5];
    float* out = (float*)d_out;

    float* w = (float*)d_ws;
    float*  sojd    = w;                    // 1024
    float*  s_self  = w + 1024;             // 1024
    float4* stats4  = (float4*)(w + 2048);  // 1024 float4 (16B-aligned)

    k1_scores<<<8, 512, 0, stream>>>(node, W_emb, b_emb, w_att, b_att,
                                     sojd, s_self);
    k2_col_stats<<<128, 256, 0, stream>>>(s_self, group, sojd, stats4);
    k3_out<<<256, 512, 0, stream>>>(node, s_self, group, sojd, stats4, out);
}

// Round 12
// 23.018 us; speedup vs baseline: 1.0463x; 1.0463x over previous
//
#include <hip/hip_runtime.h>
#include <hip/hip_bf16.h>

#define NEGC (-1e8f)

__device__ __forceinline__ float lrelu(float x) { return x >= 0.f ? x : 0.2f * x; }

// Edge-logit computation. MUST be bit-identical between the stats pass (k2)
// and the output pass (k3): the neg-mask multiplies e by -1e8, so a 1-ulp
// difference becomes ~±50 in the logit and exp() explodes. Add/mul only,
// fixed association e = ss + soj. k1 is the SINGLE producer of soj bits
// (sojd[j]); k2/k3 both reload them -> consistency by construction.
__device__ __forceinline__ void edge_pq(float ss, float soj, bool same,
                                        float& p, float& q) {
    float e = ss + soj;
    float pin = same ? e : e * NEGC;
    float nin = same ? e * NEGC : e;
    p = lrelu(pin);
    q = lrelu(nin);
}

// ---------------- Kernel 1: scores. 8 blocks x 512 thr. Produces s_self[i]
// and sojd[j] = (node[j]·u1 + c1) + b_att (the one fixed association).
__global__ __launch_bounds__(512) void k1_scores(
        const float* __restrict__ node,
        const float* __restrict__ W_emb,
        const float* __restrict__ b_emb,
        const float* __restrict__ w_att,
        const float* __restrict__ b_att,
        float* __restrict__ sojd_g, float* __restrict__ s_self_g) {
    int t = threadIdx.x;
    int b = blockIdx.x;

    __shared__ float part[1024];
    __shared__ float u1[128], u2[128];
    __shared__ float cc[2];

    // u1/u2 partials: quarter q of the e-range, column k
    {
        int k = t & 127, q = t >> 7;
        float p1 = 0.f, p2 = 0.f;
        for (int e = 32 * q; e < 32 * q + 32; ++e) {
            float w = W_emb[e * 128 + k];
            p1 += w * w_att[e];
            p2 += w * w_att[128 + e];
        }
        part[q * 256 + k] = p1;
        part[q * 256 + 128 + k] = p2;
    }
    __syncthreads();
    if (t < 128) {
        u1[t] = part[t] + part[256 + t] + part[512 + t] + part[768 + t];
    } else if (t < 256) {
        int k = t - 128;
        u2[k] = part[128 + k] + part[384 + k] + part[640 + k] + part[896 + k];
    } else if (t < 320) {              // c1 = dot(b_emb, w_att[:128])
        int l = t - 256;
        float c = b_emb[l] * w_att[l] + b_emb[64 + l] * w_att[64 + l];
        for (int off = 32; off > 0; off >>= 1) c += __shfl_xor(c, off, 64);
        if (l == 0) cc[0] = c;
    } else if (t < 384) {              // c2 = dot(b_emb, w_att[128:])
        int l = t - 320;
        float c = b_emb[l] * w_att[128 + l] + b_emb[64 + l] * w_att[192 + l];
        for (int off = 32; off > 0; off >>= 1) c += __shfl_xor(c, off, 64);
        if (l == 0) cc[1] = c;
    }
    __syncthreads();

    // scores: row = b*128 + t/4; quarter q = t&3 covers 32 elems (8 float4)
    {
        int row = b * 128 + (t >> 2);
        int q = t & 3;
        const float4* row4 = (const float4*)(node + (size_t)row * 128);
        const float4* u14 = (const float4*)u1;
        const float4* u24 = (const float4*)u2;
        float d1 = 0.f, d2 = 0.f;
#pragma unroll
        for (int k = 0; k < 8; ++k) {
            float4 x = row4[q * 8 + k];
            float4 v1 = u14[q * 8 + k];
            float4 v2 = u24[q * 8 + k];
            d1 += x.x * v1.x + x.y * v1.y + x.z * v1.z + x.w * v1.w;
            d2 += x.x * v2.x + x.y * v2.y + x.z * v2.z + x.w * v2.w;
        }
        d1 += __shfl_xor(d1, 1, 64); d1 += __shfl_xor(d1, 2, 64);
        d2 += __shfl_xor(d2, 1, 64); d2 += __shfl_xor(d2, 2, 64);
        if (q == 0) {
            sojd_g[row]   = (d1 + cc[0]) + b_att[0];  // THE association
            s_self_g[row] = d2 + cc[1];
        }
    }
}

// ---------------- Kernel 2: per-column softmax stats. One wave per column,
// 4 columns/block, register logits, shfl butterflies (R10-proven).
// Stores packed stats4[j] = (pmax, 1/psum, nmax, 1/nsum).
__global__ __launch_bounds__(256) void k2_col_stats(
        const float* __restrict__ s_self,
        const int* __restrict__ group,
        const float* __restrict__ sojd,
        float4* __restrict__ stats4) {
    int j = blockIdx.x * 4 + (threadIdx.x >> 6);
    int lane = threadIdx.x & 63;
    float soj = sojd[j];                 // exact bits k1 produced
    int gj = group[j];

    float pv[16], nv[16];
    float pmax = -3.4e38f, nmax = -3.4e38f;
#pragma unroll
    for (int k = 0; k < 16; ++k) {
        int i = lane + k * 64;
        float p, q;
        edge_pq(s_self[i], soj, group[i] == gj, p, q);
        pv[k] = p; nv[k] = q;
        pmax = fmaxf(pmax, p);
        nmax = fmaxf(nmax, q);
    }
#pragma unroll
    for (int off = 32; off > 0; off >>= 1) {
        pmax = fmaxf(pmax, __shfl_xor(pmax, off, 64));
        nmax = fmaxf(nmax, __shfl_xor(nmax, off, 64));
    }
    float ps = 0.f, ns = 0.f;
#pragma unroll
    for (int k = 0; k < 16; ++k) {
        ps += __expf(pv[k] - pmax);
        ns += __expf(nv[k] - nmax);
    }
#pragma unroll
    for (int off = 32; off > 0; off >>= 1) {
        ps += __shfl_xor(ps, off, 64);
        ns += __shfl_xor(ns, off, 64);
    }
    if (lane == 0) {
        stats4[j] = make_float4(pmax, 1.f / ps, nmax, 1.f / ns);
    }
}

// ---------------- Kernel 3: out[i,:] = sum_j A[i,j] * relu(node[j,:])
// BI=4 rows/block, 256 blocks x 512 thr (R10-proven, verbatim). A packed as
// float4 bufA[j] -> single b128 broadcast read per j in the main loop.
#define BI 4
__global__ __launch_bounds__(512) void k3_out(
        const float* __restrict__ node,
        const float* __restrict__ s_self,
        const int* __restrict__ group,
        const float* __restrict__ sojd,
        const float4* __restrict__ stats4,
        float* __restrict__ out) {
    int t = threadIdx.x;       // 0..511
    int i0 = blockIdx.x * BI;

    __shared__ float buf[8192];   // 32 KB: first 1024 float4 = bufA, then reduce
    __shared__ float ss_l[BI];
    __shared__ int   g_l[BI];
    if (t < BI) { ss_l[t] = s_self[i0 + t]; g_l[t] = group[i0 + t]; }
    __syncthreads();

    float ssr[BI]; int glr[BI];
#pragma unroll
    for (int r = 0; r < BI; ++r) { ssr[r] = ss_l[r]; glr[r] = g_l[r]; }

    float4* bufA = (float4*)buf;
#pragma unroll
    for (int e = 0; e < 2; ++e) {
        int j = t + e * 512;
        float soj = sojd[j];            // exact bits k1 produced, k2 consumed
        float4 st = stats4[j];
        int gj = group[j];
        float a[BI];
#pragma unroll
        for (int r = 0; r < BI; ++r) {
            float p, q;
            edge_pq(ssr[r], soj, gj == glr[r], p, q);
            a[r] = __expf(p - st.x) * st.y + __expf(q - st.z) * st.w;
        }
        bufA[j] = make_float4(a[0], a[1], a[2], a[3]);
    }
    __syncthreads();

    int lane = t & 31;   // float4 index within a 128-d row
    int g = t >> 5;      // j-group 0..15
    const float4* nf4 = (const float4*)node;

    float4 acc[BI];
#pragma unroll
    for (int r = 0; r < BI; ++r) acc[r] = make_float4(0.f, 0.f, 0.f, 0.f);

#pragma unroll 8
    for (int j = g; j < 1024; j += 16) {
        float4 x = nf4[(size_t)j * 32 + lane];
        float4 rn;
        rn.x = fmaxf(x.x, 0.f); rn.y = fmaxf(x.y, 0.f);
        rn.z = fmaxf(x.z, 0.f); rn.w = fmaxf(x.w, 0.f);
        float4 a4 = bufA[j];            // broadcast b128
        acc[0].x += a4.x * rn.x; acc[0].y += a4.x * rn.y;
        acc[0].z += a4.x * rn.z; acc[0].w += a4.x * rn.w;
        acc[1].x += a4.y * rn.x; acc[1].y += a4.y * rn.y;
        acc[1].z += a4.y * rn.z; acc[1].w += a4.y * rn.w;
        acc[2].x += a4.z * rn.x; acc[2].y += a4.z * rn.y;
        acc[2].z += a4.z * rn.z; acc[2].w += a4.z * rn.w;
        acc[3].x += a4.w * rn.x; acc[3].y += a4.w * rn.y;
        acc[3].z += a4.w * rn.z; acc[3].w += a4.w * rn.w;
    }

    __syncthreads();  // done reading bufA; reuse buf as reduce buffer
    float4* red = (float4*)buf;   // red[g*128 + r*32 + lane], 2048 float4
#pragma unroll
    for (int r = 0; r < BI; ++r) red[g * 128 + r * 32 + lane] = acc[r];
    __syncthreads();

    // 512 outputs (BI rows x 128 d); 1 per thread, contiguous store
    int r = t >> 7;
    int d = t & 127;
    float sum = 0.f;
#pragma unroll
    for (int gg = 0; gg < 16; ++gg)
        sum += buf[gg * 512 + r * 128 + d];
    out[(size_t)(i0 + r) * 128 + d] = sum;
}

extern "C" void kernel_launch(void* const* d_in, const int* in_sizes, int n_in,
                              void* d_out, int out_size, void* d_ws, size_t ws_size,
                              hipStream_t stream) {
    const float* node  = (const float*)d_in[0];
    const int*   group = (const int*)d_in[1];
    const float* W_emb = (const float*)d_in[2];
    const float* b_emb = (const float*)d_in[3];
    const float* w_att = (const float*)d_in[4];
    const float* b_att = (const float*)d_in[5];
    float* out = (float*)d_out;

    float* w = (float*)d_ws;
    float*  sojd    = w;                    // 1024
    float*  s_self  = w + 1024;             // 1024
    float4* stats4  = (float4*)(w + 2048);  // 1024 float4 (16B-aligned)

    k1_scores<<<8, 512, 0, stream>>>(node, W_emb, b_emb, w_att, b_att,
                                     sojd, s_self);
    k2_col_stats<<<256, 256, 0, stream>>>(s_self, group, sojd, stats4);
    k3_out<<<256, 512, 0, stream>>>(node, s_self, group, sojd, stats4, out);
}